// Round 8
// baseline (57.853 us; speedup 1.0000x reference)
//
#include <hip/hip_runtime.h>
#include <hip/hip_bf16.h>

typedef __attribute__((ext_vector_type(8))) short bf16x8;
typedef __attribute__((ext_vector_type(4))) float f32x4;

#define B_ROWS 8192
#define FDIM 128
#define WAVE_COLS 256
#define TILE_COLS 16
#define NT 16            // tiles per wave
#define NCHUNK 32        // 8192 / 256

#define GLOAD_LDS(gp, lp) __builtin_amdgcn_global_load_lds( \
    (const __attribute__((address_space(1))) unsigned*)(gp), \
    (__attribute__((address_space(3))) unsigned*)(lp), 16, 0, 0)

#define LOG2E 1.4426950408889634f

#if __has_builtin(__builtin_amdgcn_exp2f)
__device__ __forceinline__ float fast_exp2(float x) { return __builtin_amdgcn_exp2f(x); }
#else
__device__ __forceinline__ float fast_exp2(float x) {
    float r; asm("v_exp_f32 %0, %1\n\ts_nop 0" : "=v"(r) : "v"(x)); return r;
}
#endif

// ---------------- Kernel A: normalize; z1n scaled by log2(e); pos[i] exact ----------------
__global__ __launch_bounds__(256) void simclr_norm(const float* __restrict__ z1,
                                                   const float* __restrict__ z2,
                                                   __hip_bfloat16* __restrict__ z1n,
                                                   __hip_bfloat16* __restrict__ z2n,
                                                   float* __restrict__ pos) {
    int row  = (blockIdx.x * 256 + threadIdx.x) >> 6;   // one wave per row
    int lane = threadIdx.x & 63;
    int c = lane * 2;
    const float2 v1 = *(const float2*)(z1 + row * FDIM + c);
    const float2 v2 = *(const float2*)(z2 + row * FDIM + c);
    float s1 = v1.x * v1.x + v1.y * v1.y;
    float s2 = v2.x * v2.x + v2.y * v2.y;
    for (int m = 32; m > 0; m >>= 1) { s1 += __shfl_xor(s1, m); s2 += __shfl_xor(s2, m); }
    float inv1 = 1.0f / fmaxf(sqrtf(s1), 1e-12f);
    float inv2 = 1.0f / fmaxf(sqrtf(s2), 1e-12f);
    float a0 = v1.x * inv1, a1 = v1.y * inv1;
    float b0 = v2.x * inv2, b1 = v2.y * inv2;
    // S' = (log2e * z1n) . z2n  ->  2^S' == e^S in the row-sum
    z1n[row * FDIM + c]     = __float2bfloat16(a0 * LOG2E);
    z1n[row * FDIM + c + 1] = __float2bfloat16(a1 * LOG2E);
    z2n[row * FDIM + c]     = __float2bfloat16(b0);
    z2n[row * FDIM + c + 1] = __float2bfloat16(b1);
    float p = a0 * b0 + a1 * b1;                        // unscaled positive logit
    for (int m = 32; m > 0; m >>= 1) p += __shfl_xor(p, m);
    if (lane == 0) pos[row] = p;
}

// ---------------- Kernel B: barrier-FREE wave-private-LDS GEMM + exp2 + row-sum ----------------
// 256 threads / 4 fully independent waves; NO __syncthreads. Each wave owns
// 64 rows (A in regs, a[4][4]) x its OWN 256-col chunk, iterated as 16 tiles
// of 16 cols. B tile (16 cols x 128 K = 4 KB) double-buffered in a private
// 2x4KB LDS region via async global_load_lds; wave syncs only via its own
// counted s_waitcnt vmcnt(4) (next tile's 4 loads stay in flight).
// 32 KB LDS/block -> occupancy is VGPR-bound; target 3-4 blocks/CU.
// exp is a single v_exp_f32 (2^x); z1n pre-scaled by log2e.
__global__ __launch_bounds__(256) void simclr_gemm(const __hip_bfloat16* __restrict__ z1n,
                                                   const __hip_bfloat16* __restrict__ z2n,
                                                   float* __restrict__ rsPart) {
    __shared__ unsigned char smem[32768];   // 4 waves x 2 bufs x 4 KB, wave-private
    const int tid = threadIdx.x;
    const int wid = tid >> 6, lane = tid & 63;
    const int lq = lane >> 4, lr = lane & 15;
    const int rowBase = blockIdx.y * 64;               // block's (and each wave's) 64 rows
    const int chunk = blockIdx.x * 4 + wid;            // wave-private col chunk
    const int colBase = chunk * WAVE_COLS;
    unsigned char* myLds = smem + wid * 8192;

    const unsigned short* g1 = (const unsigned short*)z1n;
    const unsigned short* g2 = (const unsigned short*)z2n;

    // pre-swizzled per-lane global B sources (instr j covers B-rows j*4+lq;
    // (row&7) = (j&1)*4 + lq -> two bases by j parity). Slot s of row r holds
    // global slot s ^ (r&7) -> read addr uses the same XOR.
    const unsigned short* bsrc0 = g2 + (size_t)(colBase + lq) * FDIM + (lr ^ lq) * 8;
    const unsigned short* bsrc1 = g2 + (size_t)(colBase + lq) * FDIM + (lr ^ (4 + lq)) * 8;

    // stage tile t (16 B-rows x 128 K) into buffer byte-offset `buf`
#define STAGE(t, buf) do {                                                        \
        _Pragma("unroll")                                                         \
        for (int j = 0; j < 4; ++j) {                                             \
            const unsigned short* gp = ((j & 1) ? bsrc1 : bsrc0)                  \
                                       + (size_t)((t) * TILE_COLS + j * 4) * FDIM;\
            GLOAD_LDS(gp, myLds + (buf) + j * 1024);                              \
        }                                                                         \
    } while (0)

#define VMCNT4 asm volatile("s_waitcnt vmcnt(4)" ::: "memory")
#define VMCNT0 asm volatile("s_waitcnt vmcnt(0)" ::: "memory")

    STAGE(0, 0);

    // A fragments -> registers (once): wave's 64 rows x 128 k (L1-shared across waves)
    bf16x8 a[4][4];
#pragma unroll
    for (int m = 0; m < 4; ++m) {
        const unsigned short* rp = g1 + (size_t)(rowBase + m * 16 + lr) * FDIM + lq * 8;
#pragma unroll
        for (int kk = 0; kk < 4; ++kk)
            a[m][kk] = *(const bf16x8*)(rp + kk * 32);
    }

    // precomputed swizzled LDS read offsets (one per kk) — zero inner-loop VALU
    int rdA[4];
#pragma unroll
    for (int kk = 0; kk < 4; ++kk)
        rdA[kk] = lr * 256 + ((kk * 64 + lq * 16) ^ ((lr & 7) << 4));

    float rowsum[4][4] = {};
    const f32x4 z4 = {0.0f, 0.0f, 0.0f, 0.0f};

    // compute one 64x16 tile from buffer byte-offset `buf`
#define COMPUTE(buf) do {                                                         \
        const unsigned char* bp = myLds + (buf);                                  \
        bf16x8 b0 = *(const bf16x8*)(bp + rdA[0]);                                \
        bf16x8 b1 = *(const bf16x8*)(bp + rdA[1]);                                \
        bf16x8 b2 = *(const bf16x8*)(bp + rdA[2]);                                \
        bf16x8 b3 = *(const bf16x8*)(bp + rdA[3]);                                \
        f32x4 acc[4];                                                             \
        __builtin_amdgcn_s_setprio(1);                                            \
        _Pragma("unroll")                                                         \
        for (int m = 0; m < 4; ++m)                                               \
            acc[m] = __builtin_amdgcn_mfma_f32_16x16x32_bf16(a[m][0], b0, z4, 0, 0, 0); \
        _Pragma("unroll")                                                         \
        for (int m = 0; m < 4; ++m)                                               \
            acc[m] = __builtin_amdgcn_mfma_f32_16x16x32_bf16(a[m][1], b1, acc[m], 0, 0, 0); \
        _Pragma("unroll")                                                         \
        for (int m = 0; m < 4; ++m)                                               \
            acc[m] = __builtin_amdgcn_mfma_f32_16x16x32_bf16(a[m][2], b2, acc[m], 0, 0, 0); \
        _Pragma("unroll")                                                         \
        for (int m = 0; m < 4; ++m)                                               \
            acc[m] = __builtin_amdgcn_mfma_f32_16x16x32_bf16(a[m][3], b3, acc[m], 0, 0, 0); \
        __builtin_amdgcn_s_setprio(0);                                            \
        _Pragma("unroll")                                                         \
        for (int m = 0; m < 4; ++m)                                               \
            _Pragma("unroll")                                                     \
            for (int r = 0; r < 4; ++r)                                           \
                rowsum[m][r] += fast_exp2(acc[m][r]);                             \
    } while (0)

    // tiles 0..13: explicit 2-tile pairs -> compile-time buffer offsets
    for (int tp = 0; tp < 7; ++tp) {
        STAGE(2 * tp + 1, 4096);
        VMCNT4;
        COMPUTE(0);
        STAGE(2 * tp + 2, 0);
        VMCNT4;
        COMPUTE(4096);
    }
    // tile 14 (buf 0), staging tile 15 (buf 4096)
    STAGE(15, 4096);
    VMCNT4;
    COMPUTE(0);
    // tile 15
    VMCNT0;
    COMPUTE(4096);
#undef STAGE
#undef COMPUTE

    // reduce across the 16 col-lanes; one plain store per row (no atomics)
#pragma unroll
    for (int m = 0; m < 4; ++m)
#pragma unroll
        for (int r = 0; r < 4; ++r) {
            float s = rowsum[m][r];
            s += __shfl_xor(s, 1); s += __shfl_xor(s, 2);
            s += __shfl_xor(s, 4); s += __shfl_xor(s, 8);
            if (lr == 0)
                rsPart[chunk * B_ROWS + rowBase + m * 16 + lq * 4 + r] = s;
        }
}

// ---------------- Kernel C: loss = mean(log(rowsum) - pos) ----------------
__global__ __launch_bounds__(256) void simclr_finish(const float* __restrict__ rsPart,
                                                     const float* __restrict__ pos,
                                                     float* __restrict__ out) {
    __shared__ float red[4];
    int i = blockIdx.x * 256 + threadIdx.x;   // one thread per row, 32 blocks
    float R = 0.0f;
#pragma unroll
    for (int c = 0; c < NCHUNK; ++c) R += rsPart[c * B_ROWS + i];
    float s = logf(R) - pos[i];
    for (int m = 32; m > 0; m >>= 1) s += __shfl_xor(s, m);
    if ((threadIdx.x & 63) == 0) red[threadIdx.x >> 6] = s;
    __syncthreads();
    if (threadIdx.x == 0) {
        float v = (red[0] + red[1]) + (red[2] + red[3]);
        atomicAdd(out, v * (1.0f / (float)B_ROWS));
    }
}

extern "C" void kernel_launch(void* const* d_in, const int* in_sizes, int n_in,
                              void* d_out, int out_size, void* d_ws, size_t ws_size,
                              hipStream_t stream) {
    const float* z1 = (const float*)d_in[0];
    const float* z2 = (const float*)d_in[1];
    float* out = (float*)d_out;
    char* ws = (char*)d_ws;

    __hip_bfloat16* z1n = (__hip_bfloat16*)ws;                       // 2 MB
    __hip_bfloat16* z2n = (__hip_bfloat16*)(ws + 2097152);           // 2 MB
    float* pos          = (float*)(ws + 4194304);                    // 32 KB
    float* rsPart       = (float*)(ws + 4194304 + 32768);            // 1 MB

    hipMemsetAsync(out, 0, sizeof(float), stream);
    simclr_norm<<<B_ROWS / 4, 256, 0, stream>>>(z1, z2, z1n, z2n, pos);
    // blockIdx.x = chunk group (8 x 4 waves = 32 chunks), blockIdx.y = row
    // group (128 x 64 rows): 1024 blocks, 32KB LDS each -> 4/CU if VGPR allows.
    simclr_gemm<<<dim3(8, 128), 256, 0, stream>>>(z1n, z2n, rsPart);
    simclr_finish<<<B_ROWS / 256, 256, 0, stream>>>(rsPart, pos, out);
}